// Round 14
// baseline (59.933 us; speedup 1.0000x reference)
//
#include <hip/hip_runtime.h>
#include <hip/hip_bf16.h>
#include <math.h>

#define Bq 8
#define Nq 1024
#define Dq 256
#define Hq 8
#define HDq 32
#define LOG2E 1.44269504f

typedef __attribute__((ext_vector_type(8)))  short short8v;
typedef __attribute__((ext_vector_type(2)))  float f32x2;
typedef __attribute__((ext_vector_type(4)))  float f32x4;
typedef __attribute__((ext_vector_type(16))) float f32x16;

__device__ __forceinline__ void gload_lds16(const void* g, void* l) {
    __builtin_amdgcn_global_load_lds(
        (const __attribute__((address_space(1))) void*)g,
        (__attribute__((address_space(3))) void*)l, 16, 0, 0);
}
__device__ __forceinline__ unsigned cvtpk_bf16(float lo, float hi) {
    unsigned r;
    asm("v_cvt_pk_bf16_f32 %0, %1, %2" : "=v"(r) : "v"(lo), "v"(hi));
    return r;
}

// ---------------------------------------------------------------------------
// Kernel 1 (fused role-split):
//  blocks [0,512):   bf16 MFMA GEMM h = x*W^T + b, epilogue -> h_bT (bf16,
//                    transposed) + s_i2/s_j2 (prescaled by LOG2E)
//  blocks [512,2560): pack adj rows into bitmasks adjw[b][i][0:32)
// ---------------------------------------------------------------------------
__global__ __launch_bounds__(256) void gemm_pack(const float* __restrict__ x,
                                                 const float* __restrict__ W,
                                                 const float* __restrict__ Wb,
                                                 const float* __restrict__ a,
                                                 const int* __restrict__ adj,
                                                 __hip_bfloat16* __restrict__ h_bT,
                                                 float* __restrict__ s_i2,
                                                 float* __restrict__ s_j2,
                                                 unsigned* __restrict__ adjw) {
    __shared__ __hip_bfloat16 xs[64][68];
    __shared__ __hip_bfloat16 wsm[64][68];
    __shared__ __hip_bfloat16 ht[64][72];
    const int t = threadIdx.x;
    const int lane = t & 63, wv = t >> 6;

    if (blockIdx.x >= 512) {
        const size_t row = ((size_t)blockIdx.x - 512) * 4 + wv;   // 0..8191
        const int* ar = adj + row * Nq;
        unsigned* wr = adjw + row * 32;
        #pragma unroll
        for (int it = 0; it < 16; ++it) {
            int v = ar[it * 64 + lane];
            unsigned long long mask = __ballot(v != 0);
            if (lane == 0) {
                wr[it * 2 + 0] = (unsigned)mask;
                wr[it * 2 + 1] = (unsigned)(mask >> 32);
            }
        }
        return;
    }

    const int m0 = (blockIdx.x & 127) * 64;
    const int o0 = (blockIdx.x >> 7) * 64;
    const int lo = lane & 31, hi = lane >> 5;
    const int mw = (wv & 1) * 32, ow = (wv >> 1) * 32;
    const int b = m0 >> 10;
    f32x16 acc = 0.f;

    for (int k0 = 0; k0 < 256; k0 += 64) {
        __syncthreads();
        #pragma unroll
        for (int it = 0; it < 4; ++it) {
            int f4  = t + it * 256;
            int row = f4 >> 4;
            int c4  = (f4 & 15) * 4;
            float4 xv = *(const float4*)(x + (size_t)(m0 + row) * 256 + k0 + c4);
            float4 wv2 = *(const float4*)(W + (size_t)(o0 + row) * 256 + k0 + c4);
            union { ushort4 u; __bf16 e[4]; } xb, wb;
            xb.e[0] = (__bf16)xv.x; xb.e[1] = (__bf16)xv.y;
            xb.e[2] = (__bf16)xv.z; xb.e[3] = (__bf16)xv.w;
            wb.e[0] = (__bf16)wv2.x; wb.e[1] = (__bf16)wv2.y;
            wb.e[2] = (__bf16)wv2.z; wb.e[3] = (__bf16)wv2.w;
            *(ushort4*)(&xs[row][c4])  = xb.u;
            *(ushort4*)(&wsm[row][c4]) = wb.u;
        }
        __syncthreads();
        #pragma unroll
        for (int kk = 0; kk < 4; ++kk) {
            short8v av = *(const short8v*)(&xs[mw + lo][kk * 16 + hi * 8]);
            short8v bv = *(const short8v*)(&wsm[ow + lo][kk * 16 + hi * 8]);
            acc = __builtin_amdgcn_mfma_f32_32x32x16_bf16(av, bv, acc, 0, 0, 0);
        }
    }

    __syncthreads();
    const float bias = Wb[o0 + ow + lo];
    #pragma unroll
    for (int rg = 0; rg < 16; ++rg) {
        int row = (rg & 3) + 8 * (rg >> 2) + 4 * hi;
        float v = acc[rg] + bias;
        ht[ow + lo][mw + row] = (__hip_bfloat16)v;
    }
    __syncthreads();

    #pragma unroll
    for (int it = 0; it < 2; ++it) {
        int s8 = t + it * 256;
        int ol = s8 >> 3;
        int n8 = (s8 & 7) * 8;
        short8v v = *(const short8v*)(&ht[ol][n8]);
        int o = o0 + ol;
        size_t drow = (size_t)((b * Hq + (o >> 5)) * HDq + (o & 31));
        *(short8v*)((unsigned short*)h_bT + drow * Nq + (m0 & 1023) + n8) = v;
    }
    // s projections: 256 threads, each one 32-dot.
    {
        int which = t >> 7;
        int hd = (t >> 6) & 1, nl = t & 63;
        const float* ab = a + b * 64 + which * 32;
        float s = 0.f;
        #pragma unroll
        for (int d = 0; d < 32; ++d)
            s += (float)ht[hd * 32 + d][nl] * ab[d];
        int bh = b * Hq + (o0 >> 5) + hd;
        int n  = (m0 & 1023) + nl;
        (which ? s_j2 : s_i2)[(size_t)bh * Nq + n] = s * LOG2E;
    }
}

// ---------------------------------------------------------------------------
// Kernel 2: attention v13 — v9 chunk-256 geometry (4 chunks, 8 barriers,
// counted vmcnt(7) dbuf staging, grid-capped 4 blocks/CU so 39KB LDS is
// free) + R13 slim eval (v_cvt_pk_bf16_f32, post-exp LUT mask AND, f32x2
// packed score math, l via ones-MFMA, no epilogue shuffles).
// NOTE: launched TWICE this round as an attribution probe (idempotent).
// ---------------------------------------------------------------------------
__global__ __launch_bounds__(256, 4) void attn_v13(const __hip_bfloat16* __restrict__ h_bT,
                                                   const unsigned* __restrict__ adjw,
                                                   const float* __restrict__ s_i2,
                                                   const float* __restrict__ s_j2,
                                                   __hip_bfloat16* __restrict__ att) {
    __shared__ __hip_bfloat16 hsT[2][32][256];   // 2 x 16KB, linear rows (512B)
    __shared__ float sjs[2][256];                // 2 x 1KB
    __shared__ uint4 lut[256];                   // 4KB mask LUT
    const int t = threadIdx.x, lane = t & 63, wv = t >> 6;
    // bijective XCD swizzle: 1024 blocks = 8 XCDs x 128
    const int id = ((int)blockIdx.x & 7) * 128 + ((int)blockIdx.x >> 3);
    const int bh = id >> 4;                   // 16 blocks per bh
    const int b  = bh >> 3, hh = bh & 7;
    const int i0 = (id & 15) * 64 + wv * 16;
    const int r16 = lane & 15, jg = lane >> 4;
    const int iG = i0 + r16;
    const int key = r16 & 7;                  // read-side XOR (octet units)
    const unsigned shbase = jg * 8;

    // build mask LUT: entry[byte] = 8 bf16 half-masks (bit e -> 0xFFFF/0)
    {
        unsigned bv = t;
        unsigned w0 = ((bv & 1u)  ? 0xFFFFu : 0u) | ((bv & 2u)   ? 0xFFFF0000u : 0u);
        unsigned w1 = ((bv & 4u)  ? 0xFFFFu : 0u) | ((bv & 8u)   ? 0xFFFF0000u : 0u);
        unsigned w2 = ((bv & 16u) ? 0xFFFFu : 0u) | ((bv & 32u)  ? 0xFFFF0000u : 0u);
        unsigned w3 = ((bv & 64u) ? 0xFFFFu : 0u) | ((bv & 128u) ? 0xFFFF0000u : 0u);
        lut[t] = (uint4){w0, w1, w2, w3};
    }

    const float si = s_i2[(size_t)bh * Nq + iG];
    const f32x2 si2 = {si, si};
    const unsigned short* hb = (const unsigned short*)h_bT + (size_t)bh * HDq * Nq;
    const float* sjb = s_j2 + (size_t)bh * Nq;
    const unsigned* awp = adjw + ((size_t)b * Nq + iG) * 32;

    // stage chunk ch (256 j) into buffer nb: 4 h-gload16 (2 rows each, wave
    // owns rows wv*8..+7) + 1 sjs gload16 (all waves same dest: benign race,
    // keeps per-wave VMEM count uniform for vmcnt bookkeeping).
    auto stage = [&](int nb, int ch) {
        #pragma unroll
        for (int it = 0; it < 4; ++it) {
            int rrb = wv * 8 + it * 2;
            int rr  = rrb + (lane >> 5);
            int oct = (lane & 31) ^ (rr & 7);          // source pre-swizzle
            gload_lds16(hb + (size_t)rr * Nq + ch * 256 + (oct << 3),
                        &hsT[nb][rrb][0]);
        }
        gload_lds16(sjb + ch * 256 + lane * 4, &sjs[nb][0]);
    };

    short8v ones;
    #pragma unroll
    for (int k = 0; k < 8; ++k) ones[k] = (short)0x3F80;

    f32x4 acc0 = 0.f, acc1 = 0.f, accl = 0.f;
    uint4 qa[2], qb[2];

    // prologue: batch 0 (7 VMEM/wave: 5 gload_lds + 2 uint4 mask loads)
    stage(0, 0);
    qa[0] = *(const uint4*)(awp);
    qb[0] = *(const uint4*)(awp + 4);

    #pragma unroll
    for (int c = 0; c < 4; ++c) {
        const int cb = c & 1;
        if (c < 3) {                           // issue batch c+1 (7 VMEM/wave)
            stage(cb ^ 1, c + 1);
            qa[cb ^ 1] = *(const uint4*)(awp + (c + 1) * 8);
            qb[cb ^ 1] = *(const uint4*)(awp + (c + 1) * 8 + 4);
        }
        if (c < 3) asm volatile("s_waitcnt vmcnt(7)" ::: "memory");
        else       asm volatile("s_waitcnt vmcnt(0)" ::: "memory");
        __builtin_amdgcn_s_barrier();          // chunk c data (and LUT) visible
        __builtin_amdgcn_sched_barrier(0);
        __builtin_amdgcn_s_setprio(1);

        unsigned aw8[8] = {qa[cb].x, qa[cb].y, qa[cb].z, qa[cb].w,
                           qb[cb].x, qb[cb].y, qb[cb].z, qb[cb].w};
        const __hip_bfloat16* pr0 = &hsT[cb][r16][0];
        const __hip_bfloat16* pr1 = &hsT[cb][r16 + 16][0];

        #pragma unroll
        for (int w = 0; w < 8; ++w) {
            uint4 mk = lut[(aw8[w] >> shbase) & 0xFFu]; // 8 half-masks
            int po = ((w * 4 + jg) ^ key) << 3;          // swizzled octet
            short8v fb0 = *(const short8v*)(pr0 + po);
            short8v fb1 = *(const short8v*)(pr1 + po);
            f32x4 sv0 = *(const f32x4*)(&sjs[cb][w * 32 + jg * 8]);
            f32x4 sv1 = *(const f32x4*)(&sjs[cb][w * 32 + jg * 8 + 4]);
            f32x2 a0 = si2 + (f32x2){sv0[0], sv0[1]};
            f32x2 a1 = si2 + (f32x2){sv0[2], sv0[3]};
            f32x2 a2 = si2 + (f32x2){sv1[0], sv1[1]};
            f32x2 a3 = si2 + (f32x2){sv1[2], sv1[3]};
            a0 = __builtin_elementwise_max(a0, a0 * 0.2f);   // lrelu (log2)
            a1 = __builtin_elementwise_max(a1, a1 * 0.2f);
            a2 = __builtin_elementwise_max(a2, a2 * 0.2f);
            a3 = __builtin_elementwise_max(a3, a3 * 0.2f);
            union { short8v v; unsigned u[4]; } pa;
            pa.u[0] = cvtpk_bf16(__builtin_amdgcn_exp2f(a0.x),
                                 __builtin_amdgcn_exp2f(a0.y)) & mk.x;
            pa.u[1] = cvtpk_bf16(__builtin_amdgcn_exp2f(a1.x),
                                 __builtin_amdgcn_exp2f(a1.y)) & mk.y;
            pa.u[2] = cvtpk_bf16(__builtin_amdgcn_exp2f(a2.x),
                                 __builtin_amdgcn_exp2f(a2.y)) & mk.z;
            pa.u[3] = cvtpk_bf16(__builtin_amdgcn_exp2f(a3.x),
                                 __builtin_amdgcn_exp2f(a3.y)) & mk.w;
            acc0 = __builtin_amdgcn_mfma_f32_16x16x32_bf16(pa.v, fb0, acc0, 0, 0, 0);
            acc1 = __builtin_amdgcn_mfma_f32_16x16x32_bf16(pa.v, fb1, acc1, 0, 0, 0);
            accl = __builtin_amdgcn_mfma_f32_16x16x32_bf16(pa.v, ones, accl, 0, 0, 0);
        }
        __builtin_amdgcn_s_setprio(0);
        asm volatile("s_waitcnt lgkmcnt(0)" ::: "memory");
        __builtin_amdgcn_s_barrier();          // buf cb free for overwrite
    }

    // epilogue: rows of acc0/acc1/accl align -> no shuffles; bf16 store
    #pragma unroll
    for (int rg = 0; rg < 4; ++rg) {
        int row = jg * 4 + rg;
        float rl = 1.f / accl[rg];
        size_t base = ((size_t)b * Nq + i0 + row) * Dq + hh * HDq;
        att[base + r16]      = (__hip_bfloat16)(acc0[rg] * rl);
        att[base + 16 + r16] = (__hip_bfloat16)(acc1[rg] * rl);
    }
}

// ---------------------------------------------------------------------------
// Kernel 3: out = LN(att(bf16) + x) * gamma + beta (torch unbiased, /(std+eps))
// ---------------------------------------------------------------------------
__global__ __launch_bounds__(256) void ln_k(const __hip_bfloat16* __restrict__ att,
                                            const float* __restrict__ x,
                                            const float* __restrict__ gamma,
                                            const float* __restrict__ beta,
                                            float* __restrict__ out) {
    const int t = threadIdx.x, lane = t & 63, wv = t >> 6;
    const size_t row  = (size_t)blockIdx.x * 4 + wv;
    const size_t base = row * Dq + lane * 4;
    union { ushort4 u; __hip_bfloat16 e[4]; } av;
    av.u = *(const ushort4*)((const unsigned short*)att + base);
    float4 xv = *(const float4*)(x + base);
    float o0 = (float)av.e[0] + xv.x, o1 = (float)av.e[1] + xv.y;
    float o2 = (float)av.e[2] + xv.z, o3 = (float)av.e[3] + xv.w;
    float s  = o0 + o1 + o2 + o3;
    float sq = o0 * o0 + o1 * o1 + o2 * o2 + o3 * o3;
    #pragma unroll
    for (int off = 32; off; off >>= 1) {
        s  += __shfl_xor(s, off);
        sq += __shfl_xor(sq, off);
    }
    float mean = s * (1.f / 256.f);
    float var  = (sq - 256.f * mean * mean) * (1.f / 255.f);
    var = fmaxf(var, 0.f);
    float inv = 1.f / (sqrtf(var) + 1e-6f);
    float4 g  = *(const float4*)(gamma + lane * 4);
    float4 bt = *(const float4*)(beta + lane * 4);
    float4 ov;
    ov.x = (o0 - mean) * inv * g.x + bt.x;
    ov.y = (o1 - mean) * inv * g.y + bt.y;
    ov.z = (o2 - mean) * inv * g.z + bt.z;
    ov.w = (o3 - mean) * inv * g.w + bt.w;
    *(float4*)(out + base) = ov;
}

// ---------------------------------------------------------------------------
extern "C" void kernel_launch(void* const* d_in, const int* in_sizes, int n_in,
                              void* d_out, int out_size, void* d_ws, size_t ws_size,
                              hipStream_t stream) {
    const float* x     = (const float*)d_in[0];
    const int*   adj   = (const int*)d_in[1];
    const float* W_w   = (const float*)d_in[2];
    const float* W_b   = (const float*)d_in[3];
    const float* a     = (const float*)d_in[4];
    const float* gamma = (const float*)d_in[5];
    const float* beta  = (const float*)d_in[6];
    float* out = (float*)d_out;

    // ws: h_bT [2M bf16 = 4MB] | att [2M bf16 = 4MB] | s_i2 [64K] | s_j2 [64K]
    //     | adjw [256K u32]
    __hip_bfloat16* h_bT = (__hip_bfloat16*)d_ws;
    __hip_bfloat16* att  = (__hip_bfloat16*)((char*)d_ws + (size_t)Bq * Hq * Nq * HDq * 2);
    float* s_i2 = (float*)((char*)att + (size_t)Bq * Nq * Dq * 2);
    float* s_j2 = s_i2 + (size_t)Bq * Hq * Nq;
    unsigned* adjw = (unsigned*)(s_j2 + (size_t)Bq * Hq * Nq);

    gemm_pack<<<2560, 256, 0, stream>>>(x, W_w, W_b, a, adj, h_bT, s_i2, s_j2, adjw);
    // ATTRIBUTION PROBE: attn launched twice (idempotent). The marginal
    // total-time increase vs a single launch = attn's true duration.
    attn_v13<<<1024, 256, 0, stream>>>(h_bT, adjw, s_i2, s_j2, att);
    attn_v13<<<1024, 256, 0, stream>>>(h_bT, adjw, s_i2, s_j2, att);
    ln_k<<<2048, 256, 0, stream>>>(att, x, gamma, beta, out);
}

// Round 19
// 42.594 us; speedup vs baseline: 1.4071x; 1.4071x over previous
//
#include <hip/hip_runtime.h>
#include <hip/hip_bf16.h>
#include <math.h>

#define Bq 8
#define Nq 1024
#define Dq 256
#define Hq 8
#define HDq 32
#define LOG2E 1.44269504f

typedef __attribute__((ext_vector_type(8)))  short short8v;
typedef __attribute__((ext_vector_type(2)))  float f32x2;
typedef __attribute__((ext_vector_type(4)))  float f32x4;
typedef __attribute__((ext_vector_type(16))) float f32x16;

__device__ __forceinline__ void gload_lds16(const void* g, void* l) {
    __builtin_amdgcn_global_load_lds(
        (const __attribute__((address_space(1))) void*)g,
        (__attribute__((address_space(3))) void*)l, 16, 0, 0);
}
__device__ __forceinline__ unsigned cvtpk_bf16(float lo, float hi) {
    unsigned r;
    asm("v_cvt_pk_bf16_f32 %0, %1, %2" : "=v"(r) : "v"(lo), "v"(hi));
    return r;
}

// ---------------------------------------------------------------------------
// Kernel 1 (fused role-split):
//  blocks [0,512):   bf16 MFMA GEMM h = x*W^T + b, epilogue -> h_bT (bf16,
//                    transposed) + s_i2/s_j2 (prescaled by LOG2E)
//  blocks [512,2560): pack adj rows into bitmasks adjw[b][i][0:32)
// ---------------------------------------------------------------------------
__global__ __launch_bounds__(256) void gemm_pack(const float* __restrict__ x,
                                                 const float* __restrict__ W,
                                                 const float* __restrict__ Wb,
                                                 const float* __restrict__ a,
                                                 const int* __restrict__ adj,
                                                 __hip_bfloat16* __restrict__ h_bT,
                                                 float* __restrict__ s_i2,
                                                 float* __restrict__ s_j2,
                                                 unsigned* __restrict__ adjw) {
    __shared__ __hip_bfloat16 xs[64][68];
    __shared__ __hip_bfloat16 wsm[64][68];
    __shared__ __hip_bfloat16 ht[64][72];
    const int t = threadIdx.x;
    const int lane = t & 63, wv = t >> 6;

    if (blockIdx.x >= 512) {
        const size_t row = ((size_t)blockIdx.x - 512) * 4 + wv;   // 0..8191
        const int* ar = adj + row * Nq;
        unsigned* wr = adjw + row * 32;
        #pragma unroll
        for (int it = 0; it < 16; ++it) {
            int v = ar[it * 64 + lane];
            unsigned long long mask = __ballot(v != 0);
            if (lane == 0) {
                wr[it * 2 + 0] = (unsigned)mask;
                wr[it * 2 + 1] = (unsigned)(mask >> 32);
            }
        }
        return;
    }

    const int m0 = (blockIdx.x & 127) * 64;
    const int o0 = (blockIdx.x >> 7) * 64;
    const int lo = lane & 31, hi = lane >> 5;
    const int mw = (wv & 1) * 32, ow = (wv >> 1) * 32;
    const int b = m0 >> 10;
    f32x16 acc = 0.f;

    for (int k0 = 0; k0 < 256; k0 += 64) {
        __syncthreads();
        #pragma unroll
        for (int it = 0; it < 4; ++it) {
            int f4  = t + it * 256;
            int row = f4 >> 4;
            int c4  = (f4 & 15) * 4;
            float4 xv = *(const float4*)(x + (size_t)(m0 + row) * 256 + k0 + c4);
            float4 wv2 = *(const float4*)(W + (size_t)(o0 + row) * 256 + k0 + c4);
            union { ushort4 u; __bf16 e[4]; } xb, wb;
            xb.e[0] = (__bf16)xv.x; xb.e[1] = (__bf16)xv.y;
            xb.e[2] = (__bf16)xv.z; xb.e[3] = (__bf16)xv.w;
            wb.e[0] = (__bf16)wv2.x; wb.e[1] = (__bf16)wv2.y;
            wb.e[2] = (__bf16)wv2.z; wb.e[3] = (__bf16)wv2.w;
            *(ushort4*)(&xs[row][c4])  = xb.u;
            *(ushort4*)(&wsm[row][c4]) = wb.u;
        }
        __syncthreads();
        #pragma unroll
        for (int kk = 0; kk < 4; ++kk) {
            short8v av = *(const short8v*)(&xs[mw + lo][kk * 16 + hi * 8]);
            short8v bv = *(const short8v*)(&wsm[ow + lo][kk * 16 + hi * 8]);
            acc = __builtin_amdgcn_mfma_f32_32x32x16_bf16(av, bv, acc, 0, 0, 0);
        }
    }

    __syncthreads();
    const float bias = Wb[o0 + ow + lo];
    #pragma unroll
    for (int rg = 0; rg < 16; ++rg) {
        int row = (rg & 3) + 8 * (rg >> 2) + 4 * hi;
        float v = acc[rg] + bias;
        ht[ow + lo][mw + row] = (__hip_bfloat16)v;
    }
    __syncthreads();

    #pragma unroll
    for (int it = 0; it < 2; ++it) {
        int s8 = t + it * 256;
        int ol = s8 >> 3;
        int n8 = (s8 & 7) * 8;
        short8v v = *(const short8v*)(&ht[ol][n8]);
        int o = o0 + ol;
        size_t drow = (size_t)((b * Hq + (o >> 5)) * HDq + (o & 31));
        *(short8v*)((unsigned short*)h_bT + drow * Nq + (m0 & 1023) + n8) = v;
    }
    // s projections: 256 threads, each one 32-dot.
    {
        int which = t >> 7;
        int hd = (t >> 6) & 1, nl = t & 63;
        const float* ab = a + b * 64 + which * 32;
        float s = 0.f;
        #pragma unroll
        for (int d = 0; d < 32; ++d)
            s += (float)ht[hd * 32 + d][nl] * ab[d];
        int bh = b * Hq + (o0 >> 5) + hd;
        int n  = (m0 & 1023) + nl;
        (which ? s_j2 : s_i2)[(size_t)bh * Nq + n] = s * LOG2E;
    }
}

// ---------------------------------------------------------------------------
// Kernel 2: attention v13 — EXACT R14 source (passed twice, absmax 0.078):
// chunk-256 dbuf staging, counted vmcnt(7), 4 waves, LDS mask LUT, cvt_pk,
// f32x2 eval, l via ones-MFMA. Single launch this round (probe removed).
// v14-v17 lesson (journaled): __launch_bounds__(256,4) caps VGPR at 128;
// added register pressure spills to SCRATCH whose VMEM traffic silently
// invalidates counted vmcnt(N) -> hsT read-before-DMA race. Any future
// attn change must keep VGPR_Count <= 128 or drop counted vmcnt.
// ---------------------------------------------------------------------------
__global__ __launch_bounds__(256, 4) void attn_v13(const __hip_bfloat16* __restrict__ h_bT,
                                                   const unsigned* __restrict__ adjw,
                                                   const float* __restrict__ s_i2,
                                                   const float* __restrict__ s_j2,
                                                   __hip_bfloat16* __restrict__ att) {
    __shared__ __hip_bfloat16 hsT[2][32][256];   // 2 x 16KB, linear rows (512B)
    __shared__ float sjs[2][256];                // 2 x 1KB
    __shared__ uint4 lut[256];                   // 4KB mask LUT
    const int t = threadIdx.x, lane = t & 63, wv = t >> 6;
    // bijective XCD swizzle: 1024 blocks = 8 XCDs x 128
    const int id = ((int)blockIdx.x & 7) * 128 + ((int)blockIdx.x >> 3);
    const int bh = id >> 4;                   // 16 blocks per bh
    const int b  = bh >> 3, hh = bh & 7;
    const int i0 = (id & 15) * 64 + wv * 16;
    const int r16 = lane & 15, jg = lane >> 4;
    const int iG = i0 + r16;
    const int key = r16 & 7;                  // read-side XOR (octet units)
    const unsigned shbase = jg * 8;

    // build mask LUT: entry[byte] = 8 bf16 half-masks (bit e -> 0xFFFF/0)
    {
        unsigned bv = t;
        unsigned w0 = ((bv & 1u)  ? 0xFFFFu : 0u) | ((bv & 2u)   ? 0xFFFF0000u : 0u);
        unsigned w1 = ((bv & 4u)  ? 0xFFFFu : 0u) | ((bv & 8u)   ? 0xFFFF0000u : 0u);
        unsigned w2 = ((bv & 16u) ? 0xFFFFu : 0u) | ((bv & 32u)  ? 0xFFFF0000u : 0u);
        unsigned w3 = ((bv & 64u) ? 0xFFFFu : 0u) | ((bv & 128u) ? 0xFFFF0000u : 0u);
        lut[t] = (uint4){w0, w1, w2, w3};
    }

    const float si = s_i2[(size_t)bh * Nq + iG];
    const f32x2 si2 = {si, si};
    const unsigned short* hb = (const unsigned short*)h_bT + (size_t)bh * HDq * Nq;
    const float* sjb = s_j2 + (size_t)bh * Nq;
    const unsigned* awp = adjw + ((size_t)b * Nq + iG) * 32;

    // stage chunk ch (256 j) into buffer nb: 4 h-gload16 (2 rows each, wave
    // owns rows wv*8..+7) + 1 sjs gload16 (all waves same dest: benign race,
    // keeps per-wave VMEM count uniform for vmcnt bookkeeping).
    auto stage = [&](int nb, int ch) {
        #pragma unroll
        for (int it = 0; it < 4; ++it) {
            int rrb = wv * 8 + it * 2;
            int rr  = rrb + (lane >> 5);
            int oct = (lane & 31) ^ (rr & 7);          // source pre-swizzle
            gload_lds16(hb + (size_t)rr * Nq + ch * 256 + (oct << 3),
                        &hsT[nb][rrb][0]);
        }
        gload_lds16(sjb + ch * 256 + lane * 4, &sjs[nb][0]);
    };

    short8v ones;
    #pragma unroll
    for (int k = 0; k < 8; ++k) ones[k] = (short)0x3F80;

    f32x4 acc0 = 0.f, acc1 = 0.f, accl = 0.f;
    uint4 qa[2], qb[2];

    // prologue: batch 0 (7 VMEM/wave: 5 gload_lds + 2 uint4 mask loads)
    stage(0, 0);
    qa[0] = *(const uint4*)(awp);
    qb[0] = *(const uint4*)(awp + 4);

    #pragma unroll
    for (int c = 0; c < 4; ++c) {
        const int cb = c & 1;
        if (c < 3) {                           // issue batch c+1 (7 VMEM/wave)
            stage(cb ^ 1, c + 1);
            qa[cb ^ 1] = *(const uint4*)(awp + (c + 1) * 8);
            qb[cb ^ 1] = *(const uint4*)(awp + (c + 1) * 8 + 4);
        }
        if (c < 3) asm volatile("s_waitcnt vmcnt(7)" ::: "memory");
        else       asm volatile("s_waitcnt vmcnt(0)" ::: "memory");
        __builtin_amdgcn_s_barrier();          // chunk c data (and LUT) visible
        __builtin_amdgcn_sched_barrier(0);
        __builtin_amdgcn_s_setprio(1);

        unsigned aw8[8] = {qa[cb].x, qa[cb].y, qa[cb].z, qa[cb].w,
                           qb[cb].x, qb[cb].y, qb[cb].z, qb[cb].w};
        const __hip_bfloat16* pr0 = &hsT[cb][r16][0];
        const __hip_bfloat16* pr1 = &hsT[cb][r16 + 16][0];

        #pragma unroll
        for (int w = 0; w < 8; ++w) {
            uint4 mk = lut[(aw8[w] >> shbase) & 0xFFu]; // 8 half-masks
            int po = ((w * 4 + jg) ^ key) << 3;          // swizzled octet
            short8v fb0 = *(const short8v*)(pr0 + po);
            short8v fb1 = *(const short8v*)(pr1 + po);
            f32x4 sv0 = *(const f32x4*)(&sjs[cb][w * 32 + jg * 8]);
            f32x4 sv1 = *(const f32x4*)(&sjs[cb][w * 32 + jg * 8 + 4]);
            f32x2 a0 = si2 + (f32x2){sv0[0], sv0[1]};
            f32x2 a1 = si2 + (f32x2){sv0[2], sv0[3]};
            f32x2 a2 = si2 + (f32x2){sv1[0], sv1[1]};
            f32x2 a3 = si2 + (f32x2){sv1[2], sv1[3]};
            a0 = __builtin_elementwise_max(a0, a0 * 0.2f);   // lrelu (log2)
            a1 = __builtin_elementwise_max(a1, a1 * 0.2f);
            a2 = __builtin_elementwise_max(a2, a2 * 0.2f);
            a3 = __builtin_elementwise_max(a3, a3 * 0.2f);
            union { short8v v; unsigned u[4]; } pa;
            pa.u[0] = cvtpk_bf16(__builtin_amdgcn_exp2f(a0.x),
                                 __builtin_amdgcn_exp2f(a0.y)) & mk.x;
            pa.u[1] = cvtpk_bf16(__builtin_amdgcn_exp2f(a1.x),
                                 __builtin_amdgcn_exp2f(a1.y)) & mk.y;
            pa.u[2] = cvtpk_bf16(__builtin_amdgcn_exp2f(a2.x),
                                 __builtin_amdgcn_exp2f(a2.y)) & mk.z;
            pa.u[3] = cvtpk_bf16(__builtin_amdgcn_exp2f(a3.x),
                                 __builtin_amdgcn_exp2f(a3.y)) & mk.w;
            acc0 = __builtin_amdgcn_mfma_f32_16x16x32_bf16(pa.v, fb0, acc0, 0, 0, 0);
            acc1 = __builtin_amdgcn_mfma_f32_16x16x32_bf16(pa.v, fb1, acc1, 0, 0, 0);
            accl = __builtin_amdgcn_mfma_f32_16x16x32_bf16(pa.v, ones, accl, 0, 0, 0);
        }
        __builtin_amdgcn_s_setprio(0);
        asm volatile("s_waitcnt lgkmcnt(0)" ::: "memory");
        __builtin_amdgcn_s_barrier();          // buf cb free for overwrite
    }

    // epilogue: rows of acc0/acc1/accl align -> no shuffles; bf16 store
    #pragma unroll
    for (int rg = 0; rg < 4; ++rg) {
        int row = jg * 4 + rg;
        float rl = 1.f / accl[rg];
        size_t base = ((size_t)b * Nq + i0 + row) * Dq + hh * HDq;
        att[base + r16]      = (__hip_bfloat16)(acc0[rg] * rl);
        att[base + 16 + r16] = (__hip_bfloat16)(acc1[rg] * rl);
    }
}

// ---------------------------------------------------------------------------
// Kernel 3: out = LN(att(bf16) + x) * gamma + beta (torch unbiased, /(std+eps))
// ---------------------------------------------------------------------------
__global__ __launch_bounds__(256) void ln_k(const __hip_bfloat16* __restrict__ att,
                                            const float* __restrict__ x,
                                            const float* __restrict__ gamma,
                                            const float* __restrict__ beta,
                                            float* __restrict__ out) {
    const int t = threadIdx.x, lane = t & 63, wv = t >> 6;
    const size_t row  = (size_t)blockIdx.x * 4 + wv;
    const size_t base = row * Dq + lane * 4;
    union { ushort4 u; __hip_bfloat16 e[4]; } av;
    av.u = *(const ushort4*)((const unsigned short*)att + base);
    float4 xv = *(const float4*)(x + base);
    float o0 = (float)av.e[0] + xv.x, o1 = (float)av.e[1] + xv.y;
    float o2 = (float)av.e[2] + xv.z, o3 = (float)av.e[3] + xv.w;
    float s  = o0 + o1 + o2 + o3;
    float sq = o0 * o0 + o1 * o1 + o2 * o2 + o3 * o3;
    #pragma unroll
    for (int off = 32; off; off >>= 1) {
        s  += __shfl_xor(s, off);
        sq += __shfl_xor(sq, off);
    }
    float mean = s * (1.f / 256.f);
    float var  = (sq - 256.f * mean * mean) * (1.f / 255.f);
    var = fmaxf(var, 0.f);
    float inv = 1.f / (sqrtf(var) + 1e-6f);
    float4 g  = *(const float4*)(gamma + lane * 4);
    float4 bt = *(const float4*)(beta + lane * 4);
    float4 ov;
    ov.x = (o0 - mean) * inv * g.x + bt.x;
    ov.y = (o1 - mean) * inv * g.y + bt.y;
    ov.z = (o2 - mean) * inv * g.z + bt.z;
    ov.w = (o3 - mean) * inv * g.w + bt.w;
    *(float4*)(out + base) = ov;
}

// ---------------------------------------------------------------------------
extern "C" void kernel_launch(void* const* d_in, const int* in_sizes, int n_in,
                              void* d_out, int out_size, void* d_ws, size_t ws_size,
                              hipStream_t stream) {
    const float* x     = (const float*)d_in[0];
    const int*   adj   = (const int*)d_in[1];
    const float* W_w   = (const float*)d_in[2];
    const float* W_b   = (const float*)d_in[3];
    const float* a     = (const float*)d_in[4];
    const float* gamma = (const float*)d_in[5];
    const float* beta  = (const float*)d_in[6];
    float* out = (float*)d_out;

    // ws: h_bT [2M bf16 = 4MB] | att [2M bf16 = 4MB] | s_i2 [64K] | s_j2 [64K]
    //     | adjw [256K u32]
    __hip_bfloat16* h_bT = (__hip_bfloat16*)d_ws;
    __hip_bfloat16* att  = (__hip_bfloat16*)((char*)d_ws + (size_t)Bq * Hq * Nq * HDq * 2);
    float* s_i2 = (float*)((char*)att + (size_t)Bq * Nq * Dq * 2);
    float* s_j2 = s_i2 + (size_t)Bq * Hq * Nq;
    unsigned* adjw = (unsigned*)(s_j2 + (size_t)Bq * Hq * Nq);

    gemm_pack<<<2560, 256, 0, stream>>>(x, W_w, W_b, a, adj, h_bT, s_i2, s_j2, adjw);
    attn_v13<<<1024, 256, 0, stream>>>(h_bT, adjw, s_i2, s_j2, att);
    ln_k<<<2048, 256, 0, stream>>>(att, x, gamma, beta, out);
}